// Round 4
// baseline (680.841 us; speedup 1.0000x reference)
//
#include <hip/hip_runtime.h>

// BoxFilter r=8 (k=17), fused separable pass over [8,32,512,512] fp32.
// BARRIER-FREE + sched_barrier-PINNED 4-deep pipeline.
//  - One block = one (image, 128-row strip). grid = 1024 = 4 blocks/CU
//    (LDS 34.8 KB -> 4 resident, 16 waves/CU).
//  - Thread tid owns output columns 2*tid, 2*tid+1 for the whole strip.
//  - Horizontal 17-tap: 9 aligned float2 global loads per row per thread
//    (neighbor overlap served by L1/L2/L3).
//  - Vertical 17-tap: running sum + 17-row hsum ring in LDS, thread-private
//    columns -> no barriers anywhere.
//  - KEY CHANGE vs r1/r2: __builtin_amdgcn_sched_barrier(0) fences pin the
//    load(g+4) / compute(g) interleave. r1/r2's VGPR=52 proved hipcc
//    serialized the pipeline (4x18 live floats needs >=72 VGPR); dur was
//    identical across 1-deep and 4-deep source = compiler-defeated.
//  - Edge lanes: 9 clamped float2 loads + selects (was 18 scalar guarded).
//  - Output via nontemporal stores (native ext_vector_type for the builtin):
//    don't evict input from L3 (FETCH was 182MB < 268MB input = L3 hits).
// Zero padding matches reference; scale 1/289.

#define WW 512
#define HH 512
#define RR 8
#define KK 17
#define TPB 256
#define NSTRIP 4
#define CH (HH / NSTRIP)      // 128 rows per strip
#define NG (CH + 2 * RR)      // 144 row iterations (divisible by 4)

#define SB() __builtin_amdgcn_sched_barrier(0)

typedef float nfloat2 __attribute__((ext_vector_type(2)));  // native vec for nt-store

struct Row { float2 a[9]; };

// Load 9 float2 covering input cols [c0-8, c0+9] of row rr, zero-padded.
__device__ __forceinline__ void load_row(const float* __restrict__ xi, int rr,
                                         int c0, bool interior, Row& r) {
    if (rr < 0 || rr >= HH) {          // uniform branch (rr same for all lanes)
#pragma unroll
        for (int q = 0; q < 9; ++q) r.a[q] = make_float2(0.f, 0.f);
        return;
    }
    const float* rp = xi + (size_t)rr * WW;
    if (interior) {                    // lanes 4..251: full window in range
#pragma unroll
        for (int q = 0; q < 9; ++q)
            r.a[q] = *(const float2*)(rp + (c0 - RR) + 2 * q);
    } else {                           // 8 edge lanes: clamped loads + select
#pragma unroll
        for (int q = 0; q < 9; ++q) {
            const int i0 = c0 - RR + 2 * q;          // even -> 8B aligned
            const int i1 = i0 + 1;
            const int ic = i0 < 0 ? 0 : (i0 > WW - 2 ? WW - 2 : i0);
            const float2 v = *(const float2*)(rp + ic);
            r.a[q].x = (i0 >= 0 && i0 < WW) ? v.x : 0.f;
            r.a[q].y = (i1 >= 0 && i1 < WW) ? v.y : 0.f;
        }
    }
}

__global__ __launch_bounds__(TPB, 4)
void box_pin(const float* __restrict__ x, float* __restrict__ out) {
    __shared__ float ring[KK][WW];     // 34.8 KB: horizontal-sum history

    const int tid   = threadIdx.x;
    const int img   = blockIdx.x / NSTRIP;
    const int strip = blockIdx.x % NSTRIP;
    const int h0    = strip * CH;

    const float* xi = x   + (size_t)img * (HH * WW);
    float*       oi = out + (size_t)img * (HH * WW);

    const int  c0       = tid * 2;
    const bool interior = (tid >= 4) && (tid <= 251);

    // zero own ring columns (thread-private -> no barrier)
#pragma unroll
    for (int z = 0; z < KK; ++z)
        *(float2*)&ring[z][c0] = make_float2(0.f, 0.f);

    const float inv = 1.0f / (float)(KK * KK);
    float vs0 = 0.f, vs1 = 0.f;
    int s = 0;

#define COMPUTE(RW, G, STORE)                                                  \
    {                                                                          \
        const float2 old = *(float2*)&ring[s][c0];                             \
        const float t0 = (RW.a[0].x + RW.a[0].y) + (RW.a[1].x + RW.a[1].y);    \
        const float t1 = (RW.a[2].x + RW.a[2].y) + (RW.a[3].x + RW.a[3].y);    \
        const float t2 = (RW.a[4].x + RW.a[4].y) + (RW.a[5].x + RW.a[5].y);    \
        const float t3 = (RW.a[6].x + RW.a[6].y) + (RW.a[7].x + RW.a[7].y);    \
        const float t4 = RW.a[8].x + RW.a[8].y;                                \
        const float ssum = ((t0 + t1) + (t2 + t3)) + t4;                       \
        const float hs0 = ssum - RW.a[8].y;  /* cols c0-8 .. c0+8 */           \
        const float hs1 = ssum - RW.a[0].x;  /* cols c0-7 .. c0+9 */           \
        vs0 += hs0 - old.x;                                                    \
        vs1 += hs1 - old.y;                                                    \
        *(float2*)&ring[s][c0] = make_float2(hs0, hs1);                        \
        if (++s == KK) s = 0;                                                  \
        if (STORE) {                                                           \
            const int y = h0 + (G) - 2 * RR;                                   \
            nfloat2 o;                                                         \
            o.x = vs0 * inv;  o.y = vs1 * inv;                                 \
            __builtin_nontemporal_store(                                       \
                o, (nfloat2*)(oi + (size_t)y * WW) + tid);                     \
        }                                                                      \
    }

    // ---- 4-deep register pipeline, sched_barrier-pinned ----
    Row B0, B1, B2, B3;
    load_row(xi, h0 - RR + 0, c0, interior, B0);  SB();
    load_row(xi, h0 - RR + 1, c0, interior, B1);  SB();
    load_row(xi, h0 - RR + 2, c0, interior, B2);  SB();
    load_row(xi, h0 - RR + 3, c0, interior, B3);  SB();

    // warm-up: rows g=0..15 produce no output (y = g-16 < 0)
    for (int g = 0; g < 2 * RR; g += 4) {
        COMPUTE(B0, g, false);      SB();
        load_row(xi, h0 - RR + g + 4, c0, interior, B0);  SB();
        COMPUTE(B1, g + 1, false);  SB();
        load_row(xi, h0 - RR + g + 5, c0, interior, B1);  SB();
        COMPUTE(B2, g + 2, false);  SB();
        load_row(xi, h0 - RR + g + 6, c0, interior, B2);  SB();
        COMPUTE(B3, g + 3, false);  SB();
        load_row(xi, h0 - RR + g + 7, c0, interior, B3);  SB();
    }
    // main: rows g=16..143, every row stores an output row
    for (int g = 2 * RR; g < NG; g += 4) {
        COMPUTE(B0, g, true);       SB();
        load_row(xi, h0 - RR + g + 4, c0, interior, B0);  SB();
        COMPUTE(B1, g + 1, true);   SB();
        load_row(xi, h0 - RR + g + 5, c0, interior, B1);  SB();
        COMPUTE(B2, g + 2, true);   SB();
        load_row(xi, h0 - RR + g + 6, c0, interior, B2);  SB();
        COMPUTE(B3, g + 3, true);   SB();
        load_row(xi, h0 - RR + g + 7, c0, interior, B3);  SB();
    }
#undef COMPUTE
}

extern "C" void kernel_launch(void* const* d_in, const int* in_sizes, int n_in,
                              void* d_out, int out_size, void* d_ws, size_t ws_size,
                              hipStream_t stream) {
    const float* x   = (const float*)d_in[0];
    float*       out = (float*)d_out;
    const int nImg = in_sizes[0] / (HH * WW);   // 8*32 = 256 images
    dim3 grid(nImg * NSTRIP), block(TPB);
    box_pin<<<grid, block, 0, stream>>>(x, out);
}

// Round 6
// 612.997 us; speedup vs baseline: 1.1107x; 1.1107x over previous
//
#include <hip/hip_runtime.h>

// BoxFilter r=8 (k=17), fused separable pass over [8,32,512,512] fp32.
// BARRIER-FREE + ASM 4-DEEP PIPELINE, conservative counted vmcnt.
// Evidence r1/r2/r4: hipcc collapses any source-level pipeline (VGPR 52-64,
// dur pinned at ~300us, 19% VALU / 19% HBM / 0 conflicts = latency-bound).
// Fix: loads are inline-asm global_load_dwordx2 (cannot be sunk), 4 rows in
// flight, uniform s_waitcnt vmcnt(27) (= allow the newest 3 rows' 27 loads
// to remain outstanding; conservative vs interleaved stores -> correct in
// warm-up and steady state with NO count shaping).
//  - One block = one (image, 128-row strip); grid 1024 = 4 blocks/CU.
//  - Thread owns cols 2t,2t+1. Horizontal 17-tap from 9 float2 loads via
//    [SGPR row base + per-thread 32-bit voffset] (saddr form): column
//    offsets computed ONCE; row base advances by one scalar add.
//  - Edge cols: clamped voffsets + precomputed masks (r1/r2/r4-proven math),
//    applied only in waves 0/3 (wave-uniform branch).
//  - Vertical 17-tap: running sum + 17-row hsum ring in LDS, thread-private
//    columns -> no barriers, no conflicts beyond free 2-way.
//  - sched_barrier(0) ONLY right after each wait (rule #18).
// Zero padding matches reference; scale 1/289.

#define WW 512
#define HH 512
#define RR 8
#define KK 17
#define TPB 256
#define NSTRIP 4
#define CH (HH / NSTRIP)      // 128 rows per strip
#define NG (CH + 2 * RR)      // 144 row iterations (divisible by 4)

typedef float nfloat2 __attribute__((ext_vector_type(2)));

#define SB() __builtin_amdgcn_sched_barrier(0)
#define WAITP() do { asm volatile("s_waitcnt vmcnt(27)" ::: "memory"); SB(); } while (0)

struct Buf { nfloat2 a[9]; };

// 9 loads of one row: uniform SGPR row base + per-thread 32-bit voffsets.
__device__ __forceinline__ void load_row(const float* __restrict__ rowp,
                                         const int* __restrict__ vb, Buf& b) {
#pragma unroll
    for (int q = 0; q < 9; ++q)
        asm volatile("global_load_dwordx2 %0, %1, %2"
                     : "=&v"(b.a[q]) : "v"(vb[q]), "s"(rowp) : "memory");
}

__global__ __launch_bounds__(TPB, 4)
void box_pipe4(const float* __restrict__ x, float* __restrict__ out) {
    __shared__ float ring[KK][WW];     // 34.8 KB hsum history (thread-private cols)

    const int tid   = threadIdx.x;
    const int img   = blockIdx.x / NSTRIP;
    const int strip = blockIdx.x % NSTRIP;
    const int h0    = strip * CH;

    const float* xi = x   + (size_t)img * (HH * WW);
    float*       oi = out + (size_t)img * (HH * WW);

    const int c0 = tid * 2;

    // per-thread clamped column byte-offsets + whole-float2-block masks
    int   vb[9];
    float msk[9];
#pragma unroll
    for (int q = 0; q < 9; ++q) {
        const int cs = c0 - RR + 2 * q;                  // even -> 8B aligned
        const int cc = cs < 0 ? 0 : (cs > WW - 2 ? WW - 2 : cs);
        vb[q]  = cc * 4;
        msk[q] = (cs >= 0 && cs <= WW - 2) ? 1.f : 0.f;  // OOB is whole blocks
    }
    const int  wv    = tid >> 6;
    const bool edgew = (wv == 0) || (wv == 3);           // wave-uniform

#pragma unroll
    for (int z = 0; z < KK; ++z)
        *(nfloat2*)&ring[z][c0] = (nfloat2){0.f, 0.f};

    // rowp invariant: points at row clamp(lr, 0, HH-1); lr = next row to load
    int lr = h0 - RR;
    const float* rowp = xi + (size_t)(lr < 0 ? 0 : lr) * WW;

#define ADV()                                                                  \
    {                                                                          \
        if ((unsigned)lr <= (unsigned)(HH - 2)) rowp += WW;                    \
        ++lr;                                                                  \
    }

    // ---- prologue: 4 rows in flight ----
    Buf B0, B1, B2, B3;
    load_row(rowp, vb, B0); ADV();
    load_row(rowp, vb, B1); ADV();
    load_row(rowp, vb, B2); ADV();
    load_row(rowp, vb, B3); ADV();

    float vs0 = 0.f, vs1 = 0.f;
    int rs = 0;
    const float inv = 1.0f / (float)(KK * KK);
    float* op = oi + (size_t)h0 * WW + c0;

#define STEP(BF, G, ST)                                                        \
    {                                                                          \
        WAITP();                                                               \
        if (edgew) {                                                           \
            _Pragma("unroll")                                                  \
            for (int q = 0; q < 9; ++q) {                                      \
                BF.a[q].x *= msk[q];                                           \
                BF.a[q].y *= msk[q];                                           \
            }                                                                  \
        }                                                                      \
        const nfloat2 old = *(nfloat2*)&ring[rs][c0];                          \
        const float t0 = (BF.a[0].x + BF.a[0].y) + (BF.a[1].x + BF.a[1].y);    \
        const float t1 = (BF.a[2].x + BF.a[2].y) + (BF.a[3].x + BF.a[3].y);    \
        const float t2 = (BF.a[4].x + BF.a[4].y) + (BF.a[5].x + BF.a[5].y);    \
        const float t3 = (BF.a[6].x + BF.a[6].y) + (BF.a[7].x + BF.a[7].y);    \
        const float t4 = BF.a[8].x + BF.a[8].y;                                \
        const float ssum = ((t0 + t1) + (t2 + t3)) + t4;                       \
        const int   rrow = h0 - RR + (G);                                      \
        const float mv   = ((unsigned)rrow < (unsigned)HH) ? 1.f : 0.f;        \
        const float hs0  = (ssum - BF.a[8].y) * mv;  /* cols c0-8..c0+8 */     \
        const float hs1  = (ssum - BF.a[0].x) * mv;  /* cols c0-7..c0+9 */     \
        vs0 += hs0 - old.x;                                                    \
        vs1 += hs1 - old.y;                                                    \
        *(nfloat2*)&ring[rs][c0] = (nfloat2){hs0, hs1};                        \
        rs = (rs == KK - 1) ? 0 : rs + 1;                                      \
        if (ST) {                                                              \
            *(nfloat2*)op = (nfloat2){vs0 * inv, vs1 * inv};                   \
            op += WW;                                                          \
        }                                                                      \
        load_row(rowp, vb, BF); ADV();                                         \
    }

    for (int g = 0; g < NG; g += 4) {
        const bool st = (g >= 2 * RR);   // uniform; boundary 16 is 4-aligned
        STEP(B0, g,     st);
        STEP(B1, g + 1, st);
        STEP(B2, g + 2, st);
        STEP(B3, g + 3, st);
    }
#undef STEP
#undef ADV
}

extern "C" void kernel_launch(void* const* d_in, const int* in_sizes, int n_in,
                              void* d_out, int out_size, void* d_ws, size_t ws_size,
                              hipStream_t stream) {
    const float* x   = (const float*)d_in[0];
    float*       out = (float*)d_out;
    const int nImg = in_sizes[0] / (HH * WW);   // 8*32 = 256 images
    dim3 grid(nImg * NSTRIP), block(TPB);
    box_pipe4<<<grid, block, 0, stream>>>(x, out);
}

// Round 7
// 452.247 us; speedup vs baseline: 1.5055x; 1.3554x over previous
//
#include <hip/hip_runtime.h>

// BoxFilter r=8 (k=17), fused separable pass over [8,32,512,512] fp32.
// STAGED-DISJOINT-LOAD design (r6 post-mortem: latency theory dead -- true
// 3x deeper pipeline moved nothing. New theory: fetch BW is capped by
// in-flight VMEM *instructions* x new-bytes-per-instruction; 9 overlapping
// float2 loads carry ~57 new B per 512B instruction -> ~1.5 TB/s wall seen
// in ALL rounds. Fix: disjoint dwordx4 staging into LDS (1KB new data per
// instruction, copy-kernel-class), horizontal taps from LDS.)
//  - r0 had this traffic shape but died on __syncthreads vmcnt(0) drains
//    (444us). Here: RAW s_barrier + counted vmcnt(4) -- next stage's loads
//    are issued BEFORE the compute phase and stay in flight across it;
//    only this stage's 4 output stores remain outstanding at the wait.
//  - 256-col tile x 128-row strip per block; 1 col/thread; grid 2048.
//    LDS = ring 17x256 (17.4KB) + stage 2x4x272 (8.7KB) = 26.1KB
//    -> 6 blocks/CU = 24 waves/CU (was 16).
//  - Stage = 4 rows: wave w loads row w's 256 floats as ONE dwordx4/lane;
//    wave 0 additionally loads the 2x8-col halo (one dword/lane, masked).
//    Row/col OOB -> zeros staged (matches zero padding).
//  - Consume: 9 aligned ds_read_b64 + parity select = 17-tap hsum; vertical
//    = running sum over LDS ring (thread-private cols, no extra syncs).
// Zero padding matches reference; scale 1/289.

#define WW 512
#define HH 512
#define RR 8
#define KK 17
#define TPB 256
#define NSTRIP 4
#define CH (HH / NSTRIP)      // 128 rows per strip
#define CTILE 256
#define NTILE (WW / CTILE)    // 2
#define SROWS 4
#define NG (CH + 2 * RR)      // 144 row-slots
#define NST (NG / SROWS)      // 36 stages
#define SW (CTILE + 2 * RR)   // 272 staged floats per row

typedef float nfloat2 __attribute__((ext_vector_type(2)));
typedef float nfloat4 __attribute__((ext_vector_type(4)));

#define SB() __builtin_amdgcn_sched_barrier(0)

__global__ __launch_bounds__(TPB, 6)
void box_stage(const float* __restrict__ x, float* __restrict__ out) {
    __shared__ __align__(16) float ring[KK][CTILE];    // 17408 B
    __shared__ __align__(16) float stg[2][SROWS][SW];  // 8704 B

    const int t    = threadIdx.x;
    const int wave = t >> 6;
    const int lane = t & 63;

    const int img   = blockIdx.x >> 3;     // 8 = NTILE*NSTRIP
    const int rem   = blockIdx.x & 7;
    const int ct    = rem >> 2;            // col tile 0/1
    const int strip = rem & 3;
    const int h0    = strip * CH;

    const float* xi = x   + (size_t)img * (HH * WW);
    float*       oi = out + (size_t)img * (HH * WW);

    const int  c   = t;                    // tile col 0..255 (1 col/thread)
    const int  cb  = c & ~1;               // aligned pair base for ds reads
    const bool odd = (c & 1) != 0;
    const int  cim = ct * CTILE + c;       // image col for stores

    // halo lane mapping (wave 0 only): 4 rows x {left 8, right 8} floats
    const int  hrow  = lane >> 4;
    const int  hside = (lane >> 3) & 1;
    const int  hk    = lane & 7;
    const int  hcol  = ct * CTILE + (hside ? CTILE + hk : hk - RR);
    const bool hcolv = hside ? (ct < NTILE - 1) : (ct > 0);

    // zero own ring column
    for (int z = 0; z < KK; ++z) ring[z][c] = 0.f;

    // ---- P: issue stage-S loads (rows h0-8+4S .. +3) into registers ----
#define ISSUE_P(S, MV, HV, HMF)                                                \
    {                                                                          \
        const int rb = h0 - RR + SROWS * (S);                                  \
        const int ar = rb + wave;                                              \
        MV = (nfloat4){0.f, 0.f, 0.f, 0.f};                                    \
        if ((unsigned)ar < (unsigned)HH) {   /* wave-uniform */                \
            const float* mp = xi + (size_t)ar * WW + ct * CTILE + lane * 4;    \
            asm volatile("global_load_dwordx4 %0, %1, off"                     \
                         : "=&v"(MV) : "v"(mp) : "memory");                    \
        }                                                                      \
        HV = 0.f; HMF = 0.f;                                                   \
        if (wave == 0) {                     /* wave-uniform */                \
            const int  habs = rb + hrow;                                       \
            const bool hm   = hcolv && ((unsigned)habs < (unsigned)HH);        \
            HMF = hm ? 1.f : 0.f;                                              \
            const float* hp = xi + (size_t)(hm ? habs : 0) * WW                \
                              + (hm ? hcol : 0);                               \
            asm volatile("global_load_dword %0, %1, off"                       \
                         : "=&v"(HV) : "v"(hp) : "memory");                    \
        }                                                                      \
    }

    // ---- W: write stage-S registers into LDS buffer S&1 ----
#define WRITE_W(S, MV, HV, HMF)                                                \
    {                                                                          \
        const int nb = (S) & 1;                                                \
        *(nfloat4*)&stg[nb][wave][RR + lane * 4] = MV;                         \
        if (wave == 0)                                                         \
            stg[nb][hrow][hside ? (RR + CTILE + hk) : hk] = HV * HMF;          \
    }

    float vs = 0.f;
    int   rs = 0;
    const float inv = 1.0f / (float)(KK * KK);

    // ---- C: consume 4 staged rows from buffer S&1 ----
#define CONSUME(S)                                                             \
    {                                                                          \
        const int cur = (S) & 1;                                               \
        _Pragma("unroll")                                                      \
        for (int j = 0; j < SROWS; ++j) {                                      \
            const int g = SROWS * (S) + j;                                     \
            nfloat2 a[9];                                                      \
            _Pragma("unroll")                                                  \
            for (int q = 0; q < 9; ++q)                                        \
                a[q] = *(nfloat2*)&stg[cur][j][cb + 2 * q];                    \
            const float t0 = (a[0].x + a[0].y) + (a[1].x + a[1].y);            \
            const float t1 = (a[2].x + a[2].y) + (a[3].x + a[3].y);            \
            const float t2 = (a[4].x + a[4].y) + (a[5].x + a[5].y);            \
            const float t3 = (a[6].x + a[6].y) + (a[7].x + a[7].y);            \
            const float t4 = a[8].x + a[8].y;                                  \
            const float ssum = ((t0 + t1) + (t2 + t3)) + t4;                   \
            const float hs   = ssum - (odd ? a[0].x : a[8].y);                 \
            const float old  = ring[rs][c];                                    \
            vs += hs - old;                                                    \
            ring[rs][c] = hs;                                                  \
            rs = (rs == KK - 1) ? 0 : rs + 1;                                  \
            if (g >= 2 * RR)                                                   \
                oi[(size_t)(h0 + g - 2 * RR) * WW + cim] = vs * inv;           \
        }                                                                      \
    }

    nfloat4 mv; float hv, hmf;

    // ---- prologue: stage 0 ----
    ISSUE_P(0, mv, hv, hmf);
    asm volatile("s_waitcnt vmcnt(0)" ::: "memory"); SB();
    WRITE_W(0, mv, hv, hmf);
    asm volatile("s_waitcnt lgkmcnt(0)\n\ts_barrier" ::: "memory");

    for (int s = 0; s < NST; ++s) {
        const bool more = (s + 1 < NST);
        if (more) ISSUE_P(s + 1, mv, hv, hmf);   // in flight across consume
        CONSUME(s);                              // 4 rows; stores iff s>=4
        if (more) {
            // drain next stage's loads; leave this stage's 4 stores in flight
            if (s >= 4) { asm volatile("s_waitcnt vmcnt(4)" ::: "memory"); }
            else        { asm volatile("s_waitcnt vmcnt(0)" ::: "memory"); }
            SB();
            WRITE_W(s + 1, mv, hv, hmf);
            asm volatile("s_waitcnt lgkmcnt(0)\n\ts_barrier" ::: "memory");
        }
    }
#undef CONSUME
#undef WRITE_W
#undef ISSUE_P
}

extern "C" void kernel_launch(void* const* d_in, const int* in_sizes, int n_in,
                              void* d_out, int out_size, void* d_ws, size_t ws_size,
                              hipStream_t stream) {
    const float* x   = (const float*)d_in[0];
    float*       out = (float*)d_out;
    const int nImg = in_sizes[0] / (HH * WW);   // 8*32 = 256 images
    dim3 grid(nImg * NTILE * NSTRIP), block(TPB);
    box_stage<<<grid, block, 0, stream>>>(x, out);
}